// Round 5
// baseline (186.258 us; speedup 1.0000x reference)
//
#include <hip/hip_runtime.h>
#include <hip/hip_bf16.h>
#include <stdint.h>

// Problem dims (fixed by reference)
#define HH 224
#define WW 224
#define CC 1024
#define BB 256
#define KK (HH*WW)            // 50176
#define EPSILON_F 0.001f
#define LOG2E 1.4426950408889634f
#define INVN (1.0f/50176.0f)
// clip(v,+-2000)/N == clip(v/N, +-2000/N) since 1/N > 0
#define CLAMP_V (2000.0f/50176.0f)

// K-split: 56 chunks of 4 rows (896 k each). Tile: 256m x 64c, 4 waves (each 64m x 64c).
// grid = 16 c-tiles x 56 k-chunks = 896 blocks ~ 3 blocks/CU.
// A-fragments are loaded DIRECTLY from global (each A row is consumed by exactly one wave
// in this tiling -> the LDS round-trip for A was pure overhead). Only B (curves) goes
// through LDS. Epilogue: atomicAdd (R1-proven; ws only holds xb: R4 showed ws < 59.3 MB).
#define KCHUNKS 56
#define ROWS_PER_CHUNK 4
#define STEPS 28              // 4 rows x 7 wb; step s: r = s%4, wb = s/4

// 36 elems = 72 B rows: 16-row b128 bank starts (18*r)%32 all distinct -> <=2-way (free)
#define LDS_STRIDE 36

typedef __bf16 bf16x8 __attribute__((ext_vector_type(8)));
typedef float  f32x4  __attribute__((ext_vector_type(4)));

// ---------------- prepass: x fp32 -> bf16 -------------------------------------------------
__global__ __launch_bounds__(256)
void cvt_bf16_kernel(const float* __restrict__ x, __hip_bfloat16* __restrict__ xb, int n8) {
    int i = blockIdx.x * 256 + threadIdx.x;   // one thread per 8 elements
    if (i >= n8) return;
    const float4* p = (const float4*)(x + (size_t)i * 8);
    float4 a = p[0], b = p[1];
    union { __hip_bfloat16 h[8]; uint4 u; } o;
    o.h[0] = (__hip_bfloat16)a.x; o.h[1] = (__hip_bfloat16)a.y;
    o.h[2] = (__hip_bfloat16)a.z; o.h[3] = (__hip_bfloat16)a.w;
    o.h[4] = (__hip_bfloat16)b.x; o.h[5] = (__hip_bfloat16)b.y;
    o.h[6] = (__hip_bfloat16)b.z; o.h[7] = (__hip_bfloat16)b.w;
    *(uint4*)(xb + (size_t)i * 8) = o.u;
}

// ---------------- main fused curve-gen + GEMM --------------------------------------------
// NOTE: no min-waves arg in __launch_bounds__ (R2: (256,7) spilled the accumulator).
template <bool BF16A>
__global__ __launch_bounds__(256)
void blob_gemm_kernel(const void* __restrict__ xin,
                      const float* __restrict__ pos,
                      const float* __restrict__ sig,
                      const float* __restrict__ cwt,
                      const float* __restrict__ xs,
                      const float* __restrict__ ys,
                      float* __restrict__ out) {
    __shared__ __bf16 Bs[2][64 * LDS_STRIDE];  // B^T tile: 64 c-rows x 32 k, double-buffered
    __shared__ float  xrow[WW];
    __shared__ float  ycol[ROWS_PER_CHUNK];

    const int tid  = threadIdx.x;
    const int wave = tid >> 6;
    const int lane = tid & 63;

    // XCD-locality swizzle (dispatch round-robin heuristic, perf-only):
    // xcd = id%8 gets k-chunks [xcd*7, xcd*7+7) x all 16 c-tiles -> 3.2 MB A per XCD L2.
    const int id   = blockIdx.x;
    const int xcd  = id & 7;
    const int slot = id >> 3;                 // 0..111
    const int z    = xcd * (KCHUNKS / 8) + slot % (KCHUNKS / 8);
    const int cx   = slot / (KCHUNKS / 8);    // 0..15
    const int c0   = cx * 64;
    const int k0   = z * (ROWS_PER_CHUNK * WW);

    if (tid < WW) xrow[tid] = xs[tid];                 // x_axis
    if (tid >= WW && tid < WW + ROWS_PER_CHUNK)
        ycol[tid - WW] = ys[(z * ROWS_PER_CHUNK + (tid - WW)) * WW];  // y_axis

    // ---- per-thread curve params: one c per thread, one k-octet ----
    const int q   = tid & 3;            // k-octet within 32-wide step
    const int cr0 = tid >> 2;           // 0..63: c-row
    const int c   = c0 + cr0;
    float A2, S2, P0, P1;
    {
        float s  = sig[c];
        float w  = cwt[c];
        float s2 = s * s;
        A2 = w / (6.283185307179586f * s2 + EPSILON_F) * INVN;
        S2 = LOG2E / (2.0f * s2 + EPSILON_F);
        P0 = pos[2 * c];
        P1 = pos[2 * c + 1];
    }
    const int bs_w = cr0 * LDS_STRIDE + q * 8;

    // ---- A fragment bases (direct global): lane holds A[m=lane&15][k=(lane>>4)*8+j] ----
    const int fl = lane & 15;
    const int fk = (lane >> 4) * 8;
    const int wm = wave * 64;
    const __hip_bfloat16* afb = (const __hip_bfloat16*)xin + (size_t)(wm + fl) * KK + k0 + fk;
    const float*          aff = (const float*)xin          + (size_t)(wm + fl) * KK + k0 + fk;
    const int br_off = fl * LDS_STRIDE + fk;

    auto load_afrag = [&](int mi, int koff) -> bf16x8 {
        if (BF16A) {
            return *(const bf16x8*)(afb + (size_t)mi * 16 * KK + koff);
        } else {
            const float* p = aff + (size_t)mi * 16 * KK + koff;
            float4 f0 = *(const float4*)(p);
            float4 f1 = *(const float4*)(p + 4);
            union { __bf16 h[8]; bf16x8 v; } t;
            t.h[0] = (__bf16)f0.x; t.h[1] = (__bf16)f0.y;
            t.h[2] = (__bf16)f0.z; t.h[3] = (__bf16)f0.w;
            t.h[4] = (__bf16)f1.x; t.h[5] = (__bf16)f1.y;
            t.h[6] = (__bf16)f1.z; t.h[7] = (__bf16)f1.w;
            return t.v;
        }
    };

    f32x4 acc[4][4];
#pragma unroll
    for (int i = 0; i < 4; ++i)
#pragma unroll
        for (int j = 0; j < 4; ++j) acc[i][j] = (f32x4){0.f, 0.f, 0.f, 0.f};

    __syncthreads();   // axes ready

    float ycolr[ROWS_PER_CHUNK];
#pragma unroll
    for (int r = 0; r < ROWS_PER_CHUNK; ++r) ycolr[r] = ycol[r];

    // ---- Ex for wb=0, stage B step 0 into buffer 0, load A-frags step 0 ----
    float Ex[8];
    {
        float4 xv0 = *(const float4*)(xrow + q * 8);
        float4 xv1 = *(const float4*)(xrow + q * 8 + 4);
        float xv[8] = {xv0.x, xv0.y, xv0.z, xv0.w, xv1.x, xv1.y, xv1.z, xv1.w};
#pragma unroll
        for (int i = 0; i < 8; ++i) {
            float dx = xv[i] - P1;
            Ex[i] = __builtin_amdgcn_exp2f(-(dx * S2 * dx));
        }
        float dy  = ycolr[0] - P0;
        float eyA = __builtin_amdgcn_exp2f(-(dy * S2 * dy)) * A2;
        union { __bf16 h[8]; uint4 u; } cv;
#pragma unroll
        for (int i = 0; i < 8; ++i) {
            float v = Ex[i] * eyA;
            cv.h[i] = (__bf16)fminf(fmaxf(v, -CLAMP_V), CLAMP_V);
        }
        *(uint4*)(&Bs[0][bs_w]) = cv.u;
    }
    bf16x8 fa[4];
#pragma unroll
    for (int mi = 0; mi < 4; ++mi) fa[mi] = load_afrag(mi, 0);
    __syncthreads();   // buffer 0 ready

    // ---- main loop: compute on buf(s&1); stage B(s+1) into other buf; prefetch A(s+1) ----
    int nr = 1, nwb = 0;   // (row, wb) of step s+1 being staged
#pragma unroll 2
    for (int s = 0; s < STEPS; ++s) {
        const int cb = s & 1;

        // 1. prefetch next A fragments into registers (longest latency first)
        bf16x8 pa[4];
        if (s < STEPS - 1) {
            const int koff = nr * WW + nwb * 32;
#pragma unroll
            for (int mi = 0; mi < 4; ++mi) pa[mi] = load_afrag(mi, koff);
        }

        // 2. B fragments from LDS + 16 MFMAs
        bf16x8 fb[4];
#pragma unroll
        for (int ni = 0; ni < 4; ++ni)
            fb[ni] = *(const bf16x8*)(&Bs[cb][br_off + ni * 16 * LDS_STRIDE]);
#pragma unroll
        for (int mi = 0; mi < 4; ++mi)
#pragma unroll
            for (int ni = 0; ni < 4; ++ni)
                acc[mi][ni] = __builtin_amdgcn_mfma_f32_16x16x32_bf16(
                    fa[mi], fb[ni], acc[mi][ni], 0, 0, 0);

        // 3. stage B(s+1) into the other buffer
        if (s < STEPS - 1) {
            if (nr == 0) {   // new wb: refresh Ex (wave-uniform branch)
                float4 xv0 = *(const float4*)(xrow + nwb * 32 + q * 8);
                float4 xv1 = *(const float4*)(xrow + nwb * 32 + q * 8 + 4);
                float xv[8] = {xv0.x, xv0.y, xv0.z, xv0.w, xv1.x, xv1.y, xv1.z, xv1.w};
#pragma unroll
                for (int i = 0; i < 8; ++i) {
                    float dx = xv[i] - P1;
                    Ex[i] = __builtin_amdgcn_exp2f(-(dx * S2 * dx));
                }
            }
            float dy  = ycolr[nr] - P0;
            float eyA = __builtin_amdgcn_exp2f(-(dy * S2 * dy)) * A2;
            union { __bf16 h[8]; uint4 u; } cv;
#pragma unroll
            for (int i = 0; i < 8; ++i) {
                float v = Ex[i] * eyA;
                cv.h[i] = (__bf16)fminf(fmaxf(v, -CLAMP_V), CLAMP_V);
            }
            *(uint4*)(&Bs[cb ^ 1][bs_w]) = cv.u;
            ++nr;
            if (nr == ROWS_PER_CHUNK) { nr = 0; ++nwb; }
        }
        __syncthreads();
        if (s < STEPS - 1) {
#pragma unroll
            for (int mi = 0; mi < 4; ++mi) fa[mi] = pa[mi];
        }
    }

    // ---- epilogue: C/D layout col=lane&15, row=(lane>>4)*4+reg -> atomicAdd (K-split) ----
    const int orow = (lane >> 4) * 4;
#pragma unroll
    for (int mi = 0; mi < 4; ++mi) {
        int m = wm + mi * 16 + orow;
#pragma unroll
        for (int ni = 0; ni < 4; ++ni) {
            int cc = c0 + ni * 16 + fl;
#pragma unroll
            for (int v = 0; v < 4; ++v)
                atomicAdd(out + (size_t)(m + v) * CC + cc, acc[mi][ni][v]);
        }
    }
}

extern "C" void kernel_launch(void* const* d_in, const int* in_sizes, int n_in,
                              void* d_out, int out_size, void* d_ws, size_t ws_size,
                              hipStream_t stream) {
    const float* x   = (const float*)d_in[0];
    const float* pos = (const float*)d_in[1];
    const float* sg  = (const float*)d_in[2];
    const float* cw  = (const float*)d_in[3];
    const float* xs  = (const float*)d_in[4];
    const float* ys  = (const float*)d_in[5];
    float* out = (float*)d_out;

    // K-split partials accumulate via atomicAdd -> zero output first
    hipMemsetAsync(out, 0, (size_t)BB * CC * sizeof(float), stream);

    const int nblk = 16 * KCHUNKS;   // 896
    const size_t nx = (size_t)BB * KK;
    const size_t XB = nx * sizeof(__hip_bfloat16);   // 25.7 MB

    if (ws_size >= XB) {
        __hip_bfloat16* xb = (__hip_bfloat16*)d_ws;
        int n8 = (int)(nx / 8);
        cvt_bf16_kernel<<<(n8 + 255) / 256, 256, 0, stream>>>(x, xb, n8);
        blob_gemm_kernel<true><<<nblk, 256, 0, stream>>>(xb, pos, sg, cw, xs, ys, out);
    } else {
        blob_gemm_kernel<false><<<nblk, 256, 0, stream>>>(x, pos, sg, cw, xs, ys, out);
    }
}

// Round 6
// 180.832 us; speedup vs baseline: 1.0300x; 1.0300x over previous
//
#include <hip/hip_runtime.h>
#include <hip/hip_bf16.h>
#include <stdint.h>

// Problem dims (fixed by reference)
#define HH 224
#define WW 224
#define CC 1024
#define BB 256
#define KK (HH*WW)            // 50176
#define EPSILON_F 0.001f
#define LOG2E 1.4426950408889634f
#define INVN (1.0f/50176.0f)
// clip(v,+-2000)/N == clip(v/N, +-2000/N) since 1/N > 0
#define CLAMP_V (2000.0f/50176.0f)

// K-split: 32 chunks of 7 rows (1568 k). Tile: 256m x 64c, 4 waves (each 64m x 64c).
// grid = 16 c-tiles x 32 k-chunks = 512 blocks = 2 blocks/CU.
// Evidence-driven structure:
//  - A-fragments DIRECT from global fp32, cvt in-register (R5: A-LDS round-trip was waste;
//    no ws room for bf16 prepass + partials, ws in [32,59.2) MiB proven R4/R5)
//  - XCD swizzle: each XCD owns 4 chunks x 16 c-tiles = its full 64-block residence ->
//    chunk A-slices stay in that XCD's L2 across the x16 c-tile re-reads (R5: FETCH 200->15MB)
//  - NO atomics (R5: 14.7M device RMWs cost ~25-50us serialized; R3: 2x worse).
//    Plain stores to 32 partial copies (copy0 = d_out, 31 in ws), then reduce kernel.
#define KCHUNKS 32
#define ROWS_PER_CHUNK 7
#define STEPS 49              // r fast (7), wb slow (7)

// 36 elems = 72 B rows: 16-row b128 bank starts (18*r)%32 all distinct -> <=2-way (free)
#define LDS_STRIDE 36

typedef __bf16 bf16x8 __attribute__((ext_vector_type(8)));
typedef float  f32x4  __attribute__((ext_vector_type(4)));

// ---------------- reduce: out[i] += sum over 31 ws partial copies --------------------------
__global__ __launch_bounds__(256)
void reduce_kernel(const float* __restrict__ part, float* __restrict__ out) {
    int i = blockIdx.x * 256 + threadIdx.x;          // 65536 float4 slots
    f32x4 s = ((const f32x4*)out)[i];                // copy 0 lives in d_out
#pragma unroll
    for (int z = 0; z < KCHUNKS - 1; ++z)
        s += ((const f32x4*)part)[(size_t)z * (BB * CC / 4) + i];
    ((f32x4*)out)[i] = s;
}

// ---------------- main fused curve-gen + GEMM ---------------------------------------------
// NOTE: no min-waves arg in __launch_bounds__ (R2: (256,7) spilled the accumulator).
template <bool PARTIAL>
__global__ __launch_bounds__(256)
void blob_gemm_kernel(const float* __restrict__ x,
                      const float* __restrict__ pos,
                      const float* __restrict__ sig,
                      const float* __restrict__ cwt,
                      const float* __restrict__ xs,
                      const float* __restrict__ ys,
                      float* __restrict__ out,
                      float* __restrict__ part) {
    __shared__ __bf16 Bs[2][64 * LDS_STRIDE];  // B^T tile: 64 c-rows x 32 k, double-buffered
    __shared__ float  xrow[WW];
    __shared__ float  ycol[ROWS_PER_CHUNK];

    const int tid  = threadIdx.x;
    const int wave = tid >> 6;
    const int lane = tid & 63;

    // XCD-locality swizzle: xcd = id%8 owns chunks [xcd*4, xcd*4+4) x all 16 c-tiles.
    const int id   = blockIdx.x;
    const int xcd  = id & 7;
    const int slot = id >> 3;                 // 0..63
    const int z    = xcd * 4 + (slot & 3);    // k-chunk 0..31
    const int cx   = slot >> 2;               // c-tile 0..15
    const int c0   = cx * 64;
    const int k0   = z * (ROWS_PER_CHUNK * WW);

    if (tid < WW) xrow[tid] = xs[tid];                 // x_axis
    if (tid >= WW && tid < WW + ROWS_PER_CHUNK)
        ycol[tid - WW] = ys[(z * ROWS_PER_CHUNK + (tid - WW)) * WW];  // y_axis

    // ---- per-thread curve params: one c per thread, one k-octet ----
    const int q   = tid & 3;            // k-octet within 32-wide step
    const int cr0 = tid >> 2;           // 0..63: c-row
    const int c   = c0 + cr0;
    float A2, S2, P0, P1;
    {
        float s  = sig[c];
        float w  = cwt[c];
        float s2 = s * s;
        A2 = w / (6.283185307179586f * s2 + EPSILON_F) * INVN;
        S2 = LOG2E / (2.0f * s2 + EPSILON_F);
        P0 = pos[2 * c];
        P1 = pos[2 * c + 1];
    }
    const int bs_w = cr0 * LDS_STRIDE + q * 8;

    // ---- A fragment bases (direct global fp32): lane holds A[m=lane&15][k=(lane>>4)*8+j] ----
    const int fl = lane & 15;
    const int fk = (lane >> 4) * 8;
    const int wm = wave * 64;
    const float* aff = x + (size_t)(wm + fl) * KK + k0 + fk;
    const int br_off = fl * LDS_STRIDE + fk;

    auto cvt_frag = [](float4 f0, float4 f1) -> bf16x8 {
        union { __bf16 h[8]; bf16x8 v; } t;
        t.h[0] = (__bf16)f0.x; t.h[1] = (__bf16)f0.y;
        t.h[2] = (__bf16)f0.z; t.h[3] = (__bf16)f0.w;
        t.h[4] = (__bf16)f1.x; t.h[5] = (__bf16)f1.y;
        t.h[6] = (__bf16)f1.z; t.h[7] = (__bf16)f1.w;
        return t.v;
    };

    f32x4 acc[4][4];
#pragma unroll
    for (int i = 0; i < 4; ++i)
#pragma unroll
        for (int j = 0; j < 4; ++j) acc[i][j] = (f32x4){0.f, 0.f, 0.f, 0.f};

    __syncthreads();   // axes ready

    float ycolr[ROWS_PER_CHUNK];
#pragma unroll
    for (int r = 0; r < ROWS_PER_CHUNK; ++r) ycolr[r] = ycol[r];

    // ---- Ex for wb=0, stage B step 0 into buffer 0, load A-frags step 0 ----
    float Ex[8];
    {
        float4 xv0 = *(const float4*)(xrow + q * 8);
        float4 xv1 = *(const float4*)(xrow + q * 8 + 4);
        float xv[8] = {xv0.x, xv0.y, xv0.z, xv0.w, xv1.x, xv1.y, xv1.z, xv1.w};
#pragma unroll
        for (int i = 0; i < 8; ++i) {
            float dx = xv[i] - P1;
            Ex[i] = __builtin_amdgcn_exp2f(-(dx * S2 * dx));
        }
        float dy  = ycolr[0] - P0;
        float eyA = __builtin_amdgcn_exp2f(-(dy * S2 * dy)) * A2;
        union { __bf16 h[8]; uint4 u; } cv;
#pragma unroll
        for (int i = 0; i < 8; ++i) {
            float v = Ex[i] * eyA;
            cv.h[i] = (__bf16)fminf(fmaxf(v, -CLAMP_V), CLAMP_V);
        }
        *(uint4*)(&Bs[0][bs_w]) = cv.u;
    }
    bf16x8 fa[4];
#pragma unroll
    for (int mi = 0; mi < 4; ++mi) {
        const float* p = aff + (size_t)mi * 16 * KK;
        fa[mi] = cvt_frag(*(const float4*)p, *(const float4*)(p + 4));
    }
    __syncthreads();   // buffer 0 ready

    // ---- main loop: compute on buf(s&1); stage B(s+1) into other buf; prefetch A(s+1) ----
    int nr = 1, nwb = 0;   // (row, wb) of step s+1 being staged
#pragma unroll 2
    for (int s = 0; s < STEPS; ++s) {
        const int cb = s & 1;

        // 1. prefetch next A fragments (fp32) into registers — longest latency first
        float4 pf0[4], pf1[4];
        if (s < STEPS - 1) {
            const int koff = nr * WW + nwb * 32;
#pragma unroll
            for (int mi = 0; mi < 4; ++mi) {
                const float* p = aff + (size_t)mi * 16 * KK + koff;
                pf0[mi] = *(const float4*)(p);
                pf1[mi] = *(const float4*)(p + 4);
            }
        }

        // 2. B fragments from LDS + 16 MFMAs
        bf16x8 fb[4];
#pragma unroll
        for (int ni = 0; ni < 4; ++ni)
            fb[ni] = *(const bf16x8*)(&Bs[cb][br_off + ni * 16 * LDS_STRIDE]);
#pragma unroll
        for (int mi = 0; mi < 4; ++mi)
#pragma unroll
            for (int ni = 0; ni < 4; ++ni)
                acc[mi][ni] = __builtin_amdgcn_mfma_f32_16x16x32_bf16(
                    fa[mi], fb[ni], acc[mi][ni], 0, 0, 0);

        // 3. stage B(s+1) into the other buffer
        if (s < STEPS - 1) {
            if (nr == 0) {   // new wb: refresh Ex (wave-uniform branch)
                float4 xv0 = *(const float4*)(xrow + nwb * 32 + q * 8);
                float4 xv1 = *(const float4*)(xrow + nwb * 32 + q * 8 + 4);
                float xv[8] = {xv0.x, xv0.y, xv0.z, xv0.w, xv1.x, xv1.y, xv1.z, xv1.w};
#pragma unroll
                for (int i = 0; i < 8; ++i) {
                    float dx = xv[i] - P1;
                    Ex[i] = __builtin_amdgcn_exp2f(-(dx * S2 * dx));
                }
            }
            float dy  = ycolr[nr] - P0;
            float eyA = __builtin_amdgcn_exp2f(-(dy * S2 * dy)) * A2;
            union { __bf16 h[8]; uint4 u; } cv;
#pragma unroll
            for (int i = 0; i < 8; ++i) {
                float v = Ex[i] * eyA;
                cv.h[i] = (__bf16)fminf(fmaxf(v, -CLAMP_V), CLAMP_V);
            }
            *(uint4*)(&Bs[cb ^ 1][bs_w]) = cv.u;
            ++nr;
            if (nr == ROWS_PER_CHUNK) { nr = 0; ++nwb; }
        }
        __syncthreads();
        if (s < STEPS - 1) {
#pragma unroll
            for (int mi = 0; mi < 4; ++mi) fa[mi] = cvt_frag(pf0[mi], pf1[mi]);
        }
    }

    // ---- epilogue: C/D layout col=lane&15, row=(lane>>4)*4+reg ----
    // PARTIAL: plain stores; chunk z -> copy z (copy 0 = d_out, z>0 -> ws slab z-1).
    const int orow = (lane >> 4) * 4;
    float* base;
    if (PARTIAL) base = (z == 0) ? out : (part + (size_t)(z - 1) * BB * CC);
    else         base = out;
#pragma unroll
    for (int mi = 0; mi < 4; ++mi) {
        int m = wm + mi * 16 + orow;
#pragma unroll
        for (int ni = 0; ni < 4; ++ni) {
            int cc = c0 + ni * 16 + fl;
#pragma unroll
            for (int v = 0; v < 4; ++v) {
                if (PARTIAL)
                    base[(size_t)(m + v) * CC + cc] = acc[mi][ni][v];
                else
                    atomicAdd(base + (size_t)(m + v) * CC + cc, acc[mi][ni][v]);
            }
        }
    }
}

extern "C" void kernel_launch(void* const* d_in, const int* in_sizes, int n_in,
                              void* d_out, int out_size, void* d_ws, size_t ws_size,
                              hipStream_t stream) {
    const float* x   = (const float*)d_in[0];
    const float* pos = (const float*)d_in[1];
    const float* sg  = (const float*)d_in[2];
    const float* cw  = (const float*)d_in[3];
    const float* xs  = (const float*)d_in[4];
    const float* ys  = (const float*)d_in[5];
    float* out = (float*)d_out;

    const int nblk = 16 * KCHUNKS;                              // 512
    const size_t PSZ = (size_t)(KCHUNKS - 1) * BB * CC * 4;     // 31 MiB

    if (ws_size >= PSZ) {
        float* part = (float*)d_ws;
        // every partial copy (incl. d_out as copy 0) is fully overwritten -> no memset
        blob_gemm_kernel<true><<<nblk, 256, 0, stream>>>(x, pos, sg, cw, xs, ys, out, part);
        reduce_kernel<<<BB * CC / 4 / 256, 256, 0, stream>>>(part, out);
    } else {
        hipMemsetAsync(out, 0, (size_t)BB * CC * sizeof(float), stream);
        blob_gemm_kernel<false><<<nblk, 256, 0, stream>>>(x, pos, sg, cw, xs, ys, out, nullptr);
    }
}